// Round 5
// baseline (83.045 us; speedup 1.0000x reference)
//
#include <hip/hip_runtime.h>
#include <hip/hip_bf16.h>
#include <stdint.h>

#define N_ROWS 4096
#define D_DIM  256
#define TWO_N  8192
#define ROWB   512                       // bytes per bf16 row
#define C_EXP  2.8853900817779268f       // 2*log2(e): exp(2*dot)=2^(dot*2*log2e)

typedef __attribute__((ext_vector_type(8))) short short8;
typedef __attribute__((ext_vector_type(16))) float f32x16;

#define GLOBAL_AS __attribute__((address_space(1)))
#define LDS_AS    __attribute__((address_space(3)))

__device__ __forceinline__ unsigned bf16rne(float f) {
    unsigned u = __float_as_uint(f);
    return (u + 0x7fffu + ((u >> 16) & 1u)) >> 16;
}
__device__ __forceinline__ float bf16val(unsigned bits) {
    return __uint_as_float(bits << 16);
}

// ---------- K1: normalize -> bf16 reps, exact pos-pair sims, bf16 self-dot exp, zero rowsum ----------
__global__ __launch_bounds__(256) void kprep(const float* __restrict__ zi,
                                             const float* __restrict__ zj,
                                             unsigned short* __restrict__ reps,
                                             float* __restrict__ pos,
                                             float* __restrict__ selfexp,
                                             float* __restrict__ rowsum) {
    int wave = threadIdx.x >> 6, lane = threadIdx.x & 63;
    int k = blockIdx.x * 4 + wave;   // 0..4095
    float4 a = *(const float4*)(zi + (size_t)k * D_DIM + lane * 4);
    float4 b = *(const float4*)(zj + (size_t)k * D_DIM + lane * 4);
    float dii = a.x * a.x + a.y * a.y + a.z * a.z + a.w * a.w;
    float djj = b.x * b.x + b.y * b.y + b.z * b.z + b.w * b.w;
    float dij = a.x * b.x + a.y * b.y + a.z * b.z + a.w * b.w;
#pragma unroll
    for (int m = 1; m < 64; m <<= 1) {
        dii += __shfl_xor(dii, m, 64);
        djj += __shfl_xor(djj, m, 64);
        dij += __shfl_xor(dij, m, 64);
    }
    float si = 1.0f / fmaxf(sqrtf(dii), 1e-12f);
    float sj = 1.0f / fmaxf(sqrtf(djj), 1e-12f);

    unsigned a0 = bf16rne(a.x * si), a1 = bf16rne(a.y * si);
    unsigned a2 = bf16rne(a.z * si), a3 = bf16rne(a.w * si);
    unsigned b0 = bf16rne(b.x * sj), b1 = bf16rne(b.y * sj);
    unsigned b2 = bf16rne(b.z * sj), b3 = bf16rne(b.w * sj);
    {
        uint2 o; o.x = a0 | (a1 << 16); o.y = a2 | (a3 << 16);
        *(uint2*)(reps + (size_t)k * D_DIM + lane * 4) = o;
    }
    {
        uint2 o; o.x = b0 | (b1 << 16); o.y = b2 | (b3 << 16);
        *(uint2*)(reps + (size_t)(k + N_ROWS) * D_DIM + lane * 4) = o;
    }
    float fa0 = bf16val(a0), fa1 = bf16val(a1), fa2 = bf16val(a2), fa3 = bf16val(a3);
    float fb0 = bf16val(b0), fb1 = bf16val(b1), fb2 = bf16val(b2), fb3 = bf16val(b3);
    float sa = fa0 * fa0 + fa1 * fa1 + fa2 * fa2 + fa3 * fa3;
    float sb = fb0 * fb0 + fb1 * fb1 + fb2 * fb2 + fb3 * fb3;
#pragma unroll
    for (int m = 1; m < 64; m <<= 1) {
        sa += __shfl_xor(sa, m, 64);
        sb += __shfl_xor(sb, m, 64);
    }
    if (lane == 0) {
        float p = dij * si * sj * 2.0f;   // /TEMPERATURE
        pos[k] = p;
        pos[k + N_ROWS] = p;
        selfexp[k] = __builtin_amdgcn_exp2f(sa * C_EXP);
        selfexp[k + N_ROWS] = __builtin_amdgcn_exp2f(sb * C_EXP);
    }
    if (threadIdx.x < 8) rowsum[blockIdx.x * 8 + threadIdx.x] = 0.0f;
}

// ---------- K2: symmetric-triangle fused sim GEMM + exp row/col sums ----------
// 2080 blocks = upper triangle (rt<=ct) of 64x64 tiles of 128x128. 4 waves x 32 rows.
// ONE-SHOT staging: whole 128-col B-panel (64 KB) into LDS once, ONE barrier,
// then the full MFMA loop runs uninterrupted. A: full K=256 in regs (64 VGPR).
// reps (4 MB) is L2-resident -> no pipelining machinery (R4 post-mortem).
__global__ __launch_bounds__(256, 2) void kmain(const unsigned short* __restrict__ reps,
                                                float* __restrict__ rowsum) {
    __shared__ __align__(16) char ldsB[128 * ROWB];   // 64 KiB
    __shared__ float colpart[4 * 128];                // 2 KiB

    const int tid = threadIdx.x;
    const int wave = tid >> 6, lane = tid & 63;
    const int l31 = lane & 31, lhi = lane >> 5, x7 = l31 & 7;

    // XCD swizzle (2080 = 8*260, bijective) + triangular decode
    int i = (blockIdx.x & 7) * 260 + (blockIdx.x >> 3);
    int rt = (int)((129.0f - sqrtf(16641.0f - 8.0f * (float)i)) * 0.5f);
    while ((rt + 1) * (129 - (rt + 1)) / 2 <= i) ++rt;
    while (rt * (129 - rt) / 2 > i) --rt;
    const int ct = rt + (i - rt * (129 - rt) / 2);
    const bool diag = (rt == ct);

    const int rowbase = rt * 128 + wave * 32;
    const int colbase = ct * 128;
    const char* repsb = (const char*)reps;

    // stage whole B-panel: 64 chunks of 1KB (2 cols each), 16 per wave.
    // LDS[col][s] = G[col][s ^ (col&7)]  (16B slots; linear dest, pre-swizzled src)
#pragma unroll
    for (int i_ = 0; i_ < 16; ++i_) {
        int c_ = wave * 16 + i_;              // chunk 0..63 (wave-uniform)
        int col_ = c_ * 2 + lhi;              // 0..127
        int gs_ = l31 ^ (col_ & 7);
        const char* ga_ = repsb + (size_t)(colbase + col_) * ROWB + gs_ * 16;
        __builtin_amdgcn_global_load_lds((const GLOBAL_AS void*)ga_,
            (LDS_AS void*)(ldsB + c_ * 1024), 16, 0, 0);
    }

    // A fragments: 32 rows, full K=256 (16 k-steps), 64 VGPRs
    short8 afrag[16];
    {
        const char* ar = repsb + (size_t)(rowbase + l31) * ROWB + lhi * 16;
#pragma unroll
        for (int ks = 0; ks < 16; ++ks)
            afrag[ks] = *(const short8*)(ar + ks * 32);
    }

    __syncthreads();   // single barrier: staging + afrag drained (vmcnt 0)

    float rsum[16];
#pragma unroll
    for (int r = 0; r < 16; ++r) rsum[r] = 0.0f;
    float csum[4];

#pragma unroll
    for (int cfp = 0; cfp < 2; ++cfp) {
        f32x16 acc0, acc1;
#pragma unroll
        for (int r = 0; r < 16; ++r) { acc0[r] = 0.0f; acc1[r] = 0.0f; }

        const int cb0 = (cfp * 64 + l31) * ROWB;
        const int cb1 = (cfp * 64 + 32 + l31) * ROWB;
#pragma unroll
        for (int ks = 0; ks < 16; ++ks) {
            int ds = ((2 * ks + lhi) ^ x7) << 4;
            short8 b0 = *(const short8*)(ldsB + cb0 + ds);
            short8 b1 = *(const short8*)(ldsB + cb1 + ds);
            acc0 = __builtin_amdgcn_mfma_f32_32x32x16_bf16(afrag[ks], b0, acc0, 0, 0, 0);
            acc1 = __builtin_amdgcn_mfma_f32_32x32x16_bf16(afrag[ks], b1, acc1, 0, 0, 0);
        }

        float c0 = 0.0f, c1 = 0.0f;
#pragma unroll
        for (int r = 0; r < 16; ++r) {
            float e0 = __builtin_amdgcn_exp2f(acc0[r] * C_EXP);
            float e1 = __builtin_amdgcn_exp2f(acc1[r] * C_EXP);
            rsum[r] += e0 + e1;
            c0 += e0;
            c1 += e1;
        }
        csum[cfp * 2] = c0;
        csum[cfp * 2 + 1] = c1;
    }

    // row-partials: reduce 32 lanes sharing each row, one atomic per row
#pragma unroll
    for (int r = 0; r < 16; ++r) {
        float s = rsum[r];
        s += __shfl_xor(s, 1, 64);
        s += __shfl_xor(s, 2, 64);
        s += __shfl_xor(s, 4, 64);
        s += __shfl_xor(s, 8, 64);
        s += __shfl_xor(s, 16, 64);
        if (l31 == 0)
            atomicAdd(&rowsum[rowbase + (r & 3) + 8 * (r >> 2) + 4 * lhi], s);
    }

    // col-partials (symmetry): only off-diagonal blocks; cross-wave reduce in LDS
    if (!diag) {
#pragma unroll
        for (int cf = 0; cf < 4; ++cf) {
            float v = csum[cf];
            v += __shfl_xor(v, 32, 64);
            if (lhi == 0) colpart[wave * 128 + cf * 32 + l31] = v;
        }
        __syncthreads();
        if (tid < 128) {
            float v = colpart[tid] + colpart[128 + tid] + colpart[256 + tid] + colpart[384 + tid];
            atomicAdd(&rowsum[colbase + tid], v);
        }
    }
}

// ---------- K3: loss = mean(log(rowsum - selfexp) - pos) ----------
__global__ __launch_bounds__(1024) void kfinal(const float* __restrict__ rowsum,
                                               const float* __restrict__ pos,
                                               const float* __restrict__ selfexp,
                                               float* __restrict__ out) {
    __shared__ float red[16];
    float local = 0.0f;
    for (int r = threadIdx.x; r < TWO_N; r += 1024)
        local += __builtin_amdgcn_logf(rowsum[r] - selfexp[r]) * 0.6931471805599453f - pos[r];
#pragma unroll
    for (int m = 1; m < 64; m <<= 1) local += __shfl_xor(local, m, 64);
    if ((threadIdx.x & 63) == 0) red[threadIdx.x >> 6] = local;
    __syncthreads();
    if (threadIdx.x == 0) {
        float t = 0.0f;
#pragma unroll
        for (int i = 0; i < 16; ++i) t += red[i];
        out[0] = t * (1.0f / (float)TWO_N);
    }
}

extern "C" void kernel_launch(void* const* d_in, const int* in_sizes, int n_in,
                              void* d_out, int out_size, void* d_ws, size_t ws_size,
                              hipStream_t stream) {
    const float* zi = (const float*)d_in[0];
    const float* zj = (const float*)d_in[1];
    float* out = (float*)d_out;

    unsigned short* reps = (unsigned short*)d_ws;                       // 4 MiB
    float* rowsum = (float*)((char*)d_ws + (size_t)TWO_N * D_DIM * 2);  // 32 KiB
    float* pos = rowsum + TWO_N;                                        // 32 KiB
    float* selfexp = pos + TWO_N;                                       // 32 KiB

    kprep<<<1024, 256, 0, stream>>>(zi, zj, reps, pos, selfexp, rowsum);
    kmain<<<2080, 256, 0, stream>>>(reps, rowsum);
    kfinal<<<1, 1024, 0, stream>>>(rowsum, pos, selfexp, out);
}

// Round 6
// 74.206 us; speedup vs baseline: 1.1191x; 1.1191x over previous
//
#include <hip/hip_runtime.h>
#include <hip/hip_bf16.h>
#include <stdint.h>

#define N_ROWS 4096
#define D_DIM  256
#define TWO_N  8192
#define ROWB   512                       // bytes per bf16 row
#define C_EXP  2.8853900817779268f       // 2*log2(e): exp(2*dot)=2^(dot*2*log2e)

typedef __attribute__((ext_vector_type(8))) short short8;
typedef __attribute__((ext_vector_type(4))) float f32x4;

__device__ __forceinline__ unsigned bf16rne(float f) {
    unsigned u = __float_as_uint(f);
    return (u + 0x7fffu + ((u >> 16) & 1u)) >> 16;
}
__device__ __forceinline__ float bf16val(unsigned bits) {
    return __uint_as_float(bits << 16);
}

// ---------- K1: normalize -> bf16 reps, exact pos-pair sims, bf16 self-dot exp, zero rowsum ----------
__global__ __launch_bounds__(256) void kprep(const float* __restrict__ zi,
                                             const float* __restrict__ zj,
                                             unsigned short* __restrict__ reps,
                                             float* __restrict__ pos,
                                             float* __restrict__ selfexp,
                                             float* __restrict__ rowsum) {
    int wave = threadIdx.x >> 6, lane = threadIdx.x & 63;
    int k = blockIdx.x * 4 + wave;   // 0..4095
    float4 a = *(const float4*)(zi + (size_t)k * D_DIM + lane * 4);
    float4 b = *(const float4*)(zj + (size_t)k * D_DIM + lane * 4);
    float dii = a.x * a.x + a.y * a.y + a.z * a.z + a.w * a.w;
    float djj = b.x * b.x + b.y * b.y + b.z * b.z + b.w * b.w;
    float dij = a.x * b.x + a.y * b.y + a.z * b.z + a.w * b.w;
#pragma unroll
    for (int m = 1; m < 64; m <<= 1) {
        dii += __shfl_xor(dii, m, 64);
        djj += __shfl_xor(djj, m, 64);
        dij += __shfl_xor(dij, m, 64);
    }
    float si = 1.0f / fmaxf(sqrtf(dii), 1e-12f);
    float sj = 1.0f / fmaxf(sqrtf(djj), 1e-12f);

    unsigned a0 = bf16rne(a.x * si), a1 = bf16rne(a.y * si);
    unsigned a2 = bf16rne(a.z * si), a3 = bf16rne(a.w * si);
    unsigned b0 = bf16rne(b.x * sj), b1 = bf16rne(b.y * sj);
    unsigned b2 = bf16rne(b.z * sj), b3 = bf16rne(b.w * sj);
    {
        uint2 o; o.x = a0 | (a1 << 16); o.y = a2 | (a3 << 16);
        *(uint2*)(reps + (size_t)k * D_DIM + lane * 4) = o;
    }
    {
        uint2 o; o.x = b0 | (b1 << 16); o.y = b2 | (b3 << 16);
        *(uint2*)(reps + (size_t)(k + N_ROWS) * D_DIM + lane * 4) = o;
    }
    float fa0 = bf16val(a0), fa1 = bf16val(a1), fa2 = bf16val(a2), fa3 = bf16val(a3);
    float fb0 = bf16val(b0), fb1 = bf16val(b1), fb2 = bf16val(b2), fb3 = bf16val(b3);
    float sa = fa0 * fa0 + fa1 * fa1 + fa2 * fa2 + fa3 * fa3;
    float sb = fb0 * fb0 + fb1 * fb1 + fb2 * fb2 + fb3 * fb3;
#pragma unroll
    for (int m = 1; m < 64; m <<= 1) {
        sa += __shfl_xor(sa, m, 64);
        sb += __shfl_xor(sb, m, 64);
    }
    if (lane == 0) {
        float p = dij * si * sj * 2.0f;   // /TEMPERATURE
        pos[k] = p;
        pos[k + N_ROWS] = p;
        selfexp[k] = __builtin_amdgcn_exp2f(sa * C_EXP);
        selfexp[k + N_ROWS] = __builtin_amdgcn_exp2f(sb * C_EXP);
    }
    if (threadIdx.x < 8) rowsum[blockIdx.x * 8 + threadIdx.x] = 0.0f;
}

// ---------- K2: R1 structure + symmetry ----------
// 544 blocks = (rt in [0,64), cs in [rt/4, 16)): 128-row x 512-col bands intersecting
// the upper triangle at 64-col-tile granularity (global tile c = cs*8+ct, keep c >= 2*rt).
// 4 waves x 32 rows; 16x16x32 MFMA, 2 A-frags x 4 B-frags; reg-staged LDS B-tiles
// (XOR slot swizzle); plain __syncthreads pair per tile — exactly R1's measured-best loop.
// Tiles c >= 2rt+2 also accumulate col-partials (symmetry) into per-wave LDS, flushed once.
__global__ __launch_bounds__(256) void kmain(const unsigned short* __restrict__ reps,
                                             float* __restrict__ rowsum) {
    __shared__ __align__(16) char ldsB[64 * 512];   // 32 KiB
    __shared__ float colacc[4][512];                // 8 KiB

    const int tid = threadIdx.x;
    const int wave = tid >> 6, lane = tid & 63;
    const int l15 = lane & 15, lhi = lane >> 4;

    // XCD swizzle (544 = 8*68, bijective) + triangular band decode
    int b = (blockIdx.x & 7) * 68 + (blockIdx.x >> 3);
    int q = 0, base = 0;
    while (base + 4 * (16 - q) <= b) { base += 4 * (16 - q); ++q; }
    int rem = b - base, nb = 16 - q;
    const int rt = 4 * q + rem / nb;
    const int cs = q + rem % nb;
    const int ct_min = (2 * rt - cs * 8) > 0 ? (2 * rt - cs * 8) : 0;

    const int rowbaseW = rt * 128 + wave * 32;
    const char* repsb = (const char*)reps;

    // zero col-partial accumulator
    for (int k = tid; k < 2048; k += 256) ((float*)colacc)[k] = 0.0f;

    // A fragments: 2 row-frags x 8 k-steps, 16B each  (R1 verbatim)
    short8 afrag[2][8];
#pragma unroll
    for (int rf = 0; rf < 2; ++rf) {
        const char* arow = repsb + (size_t)(rowbaseW + rf * 16 + l15) * ROWB;
#pragma unroll
        for (int ks = 0; ks < 8; ++ks)
            afrag[rf][ks] = *(const short8*)(arow + ks * 64 + lhi * 16);
    }

    float rsum[2][4];
#pragma unroll
    for (int rf = 0; rf < 2; ++rf)
#pragma unroll
        for (int r = 0; r < 4; ++r) rsum[rf][r] = 0.0f;

    for (int ct = ct_min; ct < 8; ++ct) {
        const int c_glob = cs * 8 + ct;
        const int colbase = c_glob * 64;
        const bool do_col = (c_glob >= 2 * rt + 2);

        // stage B tile [64 cols][512 B] with slot XOR-swizzle  (R1 verbatim)
#pragma unroll
        for (int i = 0; i < 8; ++i) {
            int o = tid * 16 + i * 4096;
            int row = o >> 9;
            int slot = (o >> 4) & 31;
            uint4 v = *(const uint4*)(repsb + (size_t)(colbase + row) * ROWB + slot * 16);
            int dslot = slot ^ (row & 7);
            *(uint4*)(ldsB + row * 512 + dslot * 16) = v;
        }
        __syncthreads();

        f32x4 acc[2][4];
#pragma unroll
        for (int rf = 0; rf < 2; ++rf)
#pragma unroll
            for (int cf = 0; cf < 4; ++cf) acc[rf][cf] = (f32x4){0.f, 0.f, 0.f, 0.f};

#pragma unroll
        for (int ks = 0; ks < 8; ++ks) {
            short8 bfr[4];
#pragma unroll
            for (int cf = 0; cf < 4; ++cf) {
                int col = cf * 16 + l15;
                int slot = ks * 4 + lhi;
                int ds = slot ^ (col & 7);
                bfr[cf] = *(const short8*)(ldsB + col * 512 + ds * 16);
            }
#pragma unroll
            for (int rf = 0; rf < 2; ++rf)
#pragma unroll
                for (int cf = 0; cf < 4; ++cf)
                    acc[rf][cf] = __builtin_amdgcn_mfma_f32_16x16x32_bf16(
                        afrag[rf][ks], bfr[cf], acc[rf][cf], 0, 0, 0);
        }
        __syncthreads();

        // epilogue: uniform exp (diag self-term removed later via selfexp)
#pragma unroll
        for (int cf = 0; cf < 4; ++cf) {
            float csum = 0.0f;
#pragma unroll
            for (int rf = 0; rf < 2; ++rf) {
                f32x4 cv = acc[rf][cf];
#pragma unroll
                for (int r = 0; r < 4; ++r) {
                    float e = __builtin_amdgcn_exp2f(cv[r] * C_EXP);
                    rsum[rf][r] += e;
                    csum += e;
                }
            }
            if (do_col) {
                csum += __shfl_xor(csum, 16, 64);
                csum += __shfl_xor(csum, 32, 64);
                if (lane < 16)
                    colacc[wave][ct * 64 + cf * 16 + lane] += csum;
            }
        }
    }

    // row-partials: reduce 16 lanes sharing each row, one atomic per row  (R1 verbatim)
#pragma unroll
    for (int rf = 0; rf < 2; ++rf)
#pragma unroll
        for (int r = 0; r < 4; ++r) {
            float s = rsum[rf][r];
            s += __shfl_xor(s, 1, 64);
            s += __shfl_xor(s, 2, 64);
            s += __shfl_xor(s, 4, 64);
            s += __shfl_xor(s, 8, 64);
            if (l15 == 0)
                atomicAdd(&rowsum[rowbaseW + rf * 16 + lhi * 4 + r], s);
        }

    // col-partials (symmetry): cross-wave sum, one atomic per col
    __syncthreads();
    for (int col = tid; col < 512; col += 256) {
        int c_glob = cs * 8 + (col >> 6);
        if (c_glob >= 2 * rt + 2) {
            float v = colacc[0][col] + colacc[1][col] + colacc[2][col] + colacc[3][col];
            atomicAdd(&rowsum[cs * 512 + col], v);
        }
    }
}

// ---------- K3: loss = mean(log(rowsum - selfexp) - pos) ----------
__global__ __launch_bounds__(1024) void kfinal(const float* __restrict__ rowsum,
                                               const float* __restrict__ pos,
                                               const float* __restrict__ selfexp,
                                               float* __restrict__ out) {
    __shared__ float red[16];
    float local = 0.0f;
    for (int r = threadIdx.x; r < TWO_N; r += 1024)
        local += __builtin_amdgcn_logf(rowsum[r] - selfexp[r]) * 0.6931471805599453f - pos[r];
#pragma unroll
    for (int m = 1; m < 64; m <<= 1) local += __shfl_xor(local, m, 64);
    if ((threadIdx.x & 63) == 0) red[threadIdx.x >> 6] = local;
    __syncthreads();
    if (threadIdx.x == 0) {
        float t = 0.0f;
#pragma unroll
        for (int i = 0; i < 16; ++i) t += red[i];
        out[0] = t * (1.0f / (float)TWO_N);
    }
}

extern "C" void kernel_launch(void* const* d_in, const int* in_sizes, int n_in,
                              void* d_out, int out_size, void* d_ws, size_t ws_size,
                              hipStream_t stream) {
    const float* zi = (const float*)d_in[0];
    const float* zj = (const float*)d_in[1];
    float* out = (float*)d_out;

    unsigned short* reps = (unsigned short*)d_ws;                       // 4 MiB
    float* rowsum = (float*)((char*)d_ws + (size_t)TWO_N * D_DIM * 2);  // 32 KiB
    float* pos = rowsum + TWO_N;                                        // 32 KiB
    float* selfexp = pos + TWO_N;                                       // 32 KiB

    kprep<<<1024, 256, 0, stream>>>(zi, zj, reps, pos, selfexp, rowsum);
    kmain<<<544, 256, 0, stream>>>(reps, rowsum);
    kfinal<<<1, 1024, 0, stream>>>(rowsum, pos, selfexp, out);
}